// Round 5
// baseline (3520.344 us; speedup 1.0000x reference)
//
#include <hip/hip_runtime.h>
#include <stdint.h>

// B=64, T=512, D=512, U=1024, 4U=4096
// Workspace:
//   xb    : [T*64][512] bf16 = 33,554,432  (x as [t][b][d], bf16)
//   hbuf  : [2][64][512] u32 (packed bf16 pairs) = 262,144
//   flags : u32[256][32] = 32,768 ; flags[wg*32 + wave] — per-WAVE flag, the 4
//           wave-flags of a WG share one 128-B line (consumer: 1 line/lane).
#define WS_XB   0LL
#define WS_H    33554432LL
#define WS_FLAG 33816576LL

typedef unsigned short u16;
typedef unsigned int   u32;
typedef unsigned long long u64;
typedef __attribute__((ext_vector_type(8))) short short8;
typedef __attribute__((ext_vector_type(4))) float f32x4;

__device__ __forceinline__ u16 f2bf(float f) {
  unsigned u = __float_as_uint(f);
  u += 0x7FFFu + ((u >> 16) & 1u);   // round-to-nearest-even
  return (u16)(u >> 16);
}
__device__ __forceinline__ float fast_tanh(float x) {
  float e = __expf(2.f * x);
  return 1.f - 2.f / (e + 1.f);
}

// ---------- conv: x [64][512][512] f32 -> xb [(t*64+b)][512] bf16 ----------
__global__ void conv_x(const float* __restrict__ x, u16* __restrict__ xb) {
  long gid = (long)blockIdx.x * blockDim.x + threadIdx.x;  // 2,097,152 threads
  long sr = gid >> 6;            // source row = b*512 + t
  int  d0 = (int)(gid & 63) * 8;
  int  b = (int)(sr >> 9), t = (int)(sr & 511);
  const float* src = x + sr * 512 + d0;
  float4 v0 = *(const float4*)(src);
  float4 v1 = *(const float4*)(src + 4);
  u16 tmp[8] = {f2bf(v0.x), f2bf(v0.y), f2bf(v0.z), f2bf(v0.w),
                f2bf(v1.x), f2bf(v1.y), f2bf(v1.z), f2bf(v1.w)};
  *(short8*)(xb + ((long)t * 64 + b) * 512 + d0) = *(short8*)tmp;
}

// ---------- fused LSTM: 256 WGs = 4 batch-groups x 64 u-tiles, persistent ----------
// Wave-factored exchange: wave w's payload fetch covers exactly producers
// ut' in [16w, 16w+16), so each wave drains+flags its own publish and polls
// only its 16 producer WGs (x4 wave-flags, one line per lane). ONE raw
// s_barrier per step (smH ready); x-prefetch is 2 steps ahead and stays in
// flight across the barrier; the 16 x-MFMAs run inside the store-ack window.
// Parity safety: sync4 couples each WG's 4 waves and the union of their
// producer sets is all 64 WGs => publish of h_{t+1} transitively follows
// every WG's completed reads of h_{t-1} (r0's 2-step-skew argument).
__launch_bounds__(256, 1)
__global__ void lstm_fused(const float* __restrict__ kern, const float* __restrict__ rec,
                           const u16* __restrict__ xb, u32* __restrict__ hbuf,
                           u32* __restrict__ flags, float* __restrict__ out) {
  __shared__ u16   smH[2][32 * 64 * 8];   // 2 x 32,768 B, frag-ordered, dbuf
  __shared__ float zscr[4][16][20];       // per-wave z transpose scratch (pad 20)

  const int bid = blockIdx.x;
  const int bg = bid >> 6;   // 0..3 batch group (64 WGs each)
  const int ut = bid & 63;   // 0..63 u tile
  const int tid = threadIdx.x;
  const int w = tid >> 6, lane = tid & 63;
  const int quad = lane >> 4, n15 = lane & 15;
  const int gate = n15 >> 2, uu = n15 & 3;
  const int rowE = quad * 4 + gate;       // elementwise/publish row

  // ---- one-time: 48 register B-fragments, gate-local columns ----
  // wave w's col(n15) = gate*1024 + ut*16 + w*4 + uu
  short8 wf[48];
  const size_t gcol = (size_t)gate * 1024 + (size_t)ut * 16 + (size_t)(w * 4 + uu);
#pragma unroll
  for (int ks = 0; ks < 32; ++ks) {
    u16 tmp[8];
#pragma unroll
    for (int j = 0; j < 8; ++j)
      tmp[j] = f2bf(rec[(size_t)(ks * 32 + quad * 8 + j) * 4096 + gcol]);
    wf[ks] = *(short8*)tmp;
  }
#pragma unroll
  for (int ks = 0; ks < 16; ++ks) {
    u16 tmp[8];
#pragma unroll
    for (int j = 0; j < 8; ++j)
      tmp[j] = f2bf(kern[(size_t)(ks * 32 + quad * 8 + j) * 4096 + gcol]);
    wf[32 + ks] = *(short8*)tmp;
  }

  float c = 0.f;

  // ---- prologue: h0 = 0 in smH[0]; x0 -> acc; x1 -> xf ----
#pragma unroll
  for (int j = 0; j < 8; ++j)
    *(uint4*)(&smH[0][(tid + j * 256) * 8]) = (uint4){0u, 0u, 0u, 0u};

  short8 xf[16];
  {
    const u16* xr = xb + (size_t)(bg * 16 + n15) * 512 + quad * 8;
#pragma unroll
    for (int ks = 0; ks < 16; ++ks) xf[ks] = *(const short8*)(xr + ks * 32);
  }
  f32x4 acc0 = {0.f, 0.f, 0.f, 0.f}, acc1 = {0.f, 0.f, 0.f, 0.f};
#pragma unroll
  for (int ks = 0; ks < 16; ks += 2) {
    acc0 = __builtin_amdgcn_mfma_f32_16x16x32_bf16(xf[ks], wf[32 + ks], acc0, 0, 0, 0);
    acc1 = __builtin_amdgcn_mfma_f32_16x16x32_bf16(xf[ks + 1], wf[33 + ks], acc1, 0, 0, 0);
  }
  {
    const u16* xr = xb + ((size_t)1 * 64 + bg * 16 + n15) * 512 + quad * 8;
#pragma unroll
    for (int ks = 0; ks < 16; ++ks) xf[ks] = *(const short8*)(xr + ks * 32);
  }
  __syncthreads();

#define X16_MFMA                                                                   \
  _Pragma("unroll")                                                                \
  for (int ks2 = 0; ks2 < 16; ks2 += 2) {                                          \
    acc0 = __builtin_amdgcn_mfma_f32_16x16x32_bf16(xf[ks2], wf[32 + ks2], acc0, 0, 0, 0);     \
    acc1 = __builtin_amdgcn_mfma_f32_16x16x32_bf16(xf[ks2 + 1], wf[33 + ks2], acc1, 0, 0, 0); \
  }

#define PAYLOAD_LOAD                                                               \
  {                                                                                \
    const u32* hs = hbuf + (size_t)pb * 32768 + (size_t)(bg * 16 + n15) * 512 + quad * 4; \
    _Pragma("unroll")                                                              \
    for (int kk = 0; kk < 8; ++kk) {                                               \
      const u64* src = (const u64*)(hs + (w * 8 + kk) * 16);                       \
      pay[2 * kk]     = __hip_atomic_load(src,     __ATOMIC_RELAXED, __HIP_MEMORY_SCOPE_AGENT); \
      pay[2 * kk + 1] = __hip_atomic_load(src + 1, __ATOMIC_RELAXED, __HIP_MEMORY_SCOPE_AGENT); \
    }                                                                              \
  }

#define OWN8(BASE)                                                                 \
  _Pragma("unroll")                                                                \
  for (int kk = 0; kk < 8; ++kk) {                                                 \
    union { u64 q[2]; short8 s; u32 d[4]; } uo;                                    \
    uo.q[0] = pay[2 * kk]; uo.q[1] = pay[2 * kk + 1];                              \
    if (kk & 1) acc1 = __builtin_amdgcn_mfma_f32_16x16x32_bf16(uo.s, wf[(BASE) + kk], acc1, 0, 0, 0); \
    else        acc0 = __builtin_amdgcn_mfma_f32_16x16x32_bf16(uo.s, wf[(BASE) + kk], acc0, 0, 0, 0); \
    *(uint4*)(smH[pb] + (((BASE) + kk) * 64 + lane) * 8) =                         \
        (uint4){uo.d[0], uo.d[1], uo.d[2], uo.d[3]};                               \
  }

  for (int t = 0; t < 512; ++t) {
    // ---- foreign 24 h-MFMAs from smH[t&1] (own 8 were done pre-barrier) ----
    const u16* sh = smH[t & 1];
#pragma unroll
    for (int g = 0; g < 4; ++g) {
      if (g == w) continue;                       // wave-uniform skip
#pragma unroll
      for (int kk = 0; kk < 8; kk += 2) {
        const int ks = g * 8 + kk;
        short8 a0 = *(const short8*)(sh + (ks * 64 + lane) * 8);
        acc0 = __builtin_amdgcn_mfma_f32_16x16x32_bf16(a0, wf[ks], acc0, 0, 0, 0);
        short8 a1 = *(const short8*)(sh + ((ks + 1) * 64 + lane) * 8);
        acc1 = __builtin_amdgcn_mfma_f32_16x16x32_bf16(a1, wf[ks + 1], acc1, 0, 0, 0);
      }
    }

    // ---- within-wave gate transpose via private LDS scratch (no barrier) ----
    const int cw = uu * 4 + gate;
    zscr[w][quad * 4 + 0][cw] = acc0[0] + acc1[0];
    zscr[w][quad * 4 + 1][cw] = acc0[1] + acc1[1];
    zscr[w][quad * 4 + 2][cw] = acc0[2] + acc1[2];
    zscr[w][quad * 4 + 3][cw] = acc0[3] + acc1[3];
    asm volatile("s_waitcnt lgkmcnt(0)" ::: "memory");
    __builtin_amdgcn_sched_barrier(0);
    float4 zv = *(const float4*)&zscr[w][rowE][uu * 4];   // (i,f,g,o)

    float ig = 1.f / (1.f + __expf(-zv.x));
    float fg = 1.f / (1.f + __expf(-zv.y));
    float gg = fast_tanh(zv.z);
    float og = 1.f / (1.f + __expf(-zv.w));
    c = fg * c + ig * gg;
    float h = og * fast_tanh(c);

    if (t == 511) {
      out[(size_t)(bg * 16 + rowE) * 1024 + (size_t)(ut * 16 + w * 4 + uu)] = h;
      break;
    }

    const int pb = (t + 1) & 1;
    const u32 tag = (u32)(t + 1);

    // ---- publish packed: pair via shfl, even-uu lanes store one u32 ----
    {
      u16 hu = f2bf(h);
      int other = __shfl_xor((int)(unsigned)hu, 1);
      if ((uu & 1) == 0) {
        u32 pw = (u32)hu | ((u32)(unsigned)other << 16);
        __hip_atomic_store(&hbuf[(size_t)pb * 32768 + (size_t)(bg * 16 + rowE) * 512
                                 + ut * 8 + w * 2 + (uu >> 1)],
                           pw, __ATOMIC_RELAXED, __HIP_MEMORY_SCOPE_AGENT);
      }
    }

    // ---- x-MFMAs for t+1 (xf loaded 2 steps ahead) inside the ack window ----
    acc0 = (f32x4){0.f, 0.f, 0.f, 0.f};
    acc1 = (f32x4){0.f, 0.f, 0.f, 0.f};
    X16_MFMA;

    // ---- per-wave drain + per-wave flag (no barrier before the flag) ----
    asm volatile("s_waitcnt vmcnt(0)" ::: "memory");
    if (lane == 0)
      __hip_atomic_store(&flags[(bg * 64 + ut) * 32 + w], tag,
                         __ATOMIC_RELAXED, __HIP_MEMORY_SCOPE_AGENT);

    // ---- x_{t+2} prefetch issue (consumed next iter; in flight across barrier)
    {
      const int tn = (t + 2 < 512) ? (t + 2) : 511;
      const u16* xr = xb + ((size_t)tn * 64 + bg * 16 + n15) * 512 + quad * 8;
#pragma unroll
      for (int ks2 = 0; ks2 < 16; ++ks2) xf[ks2] = *(const short8*)(xr + ks2 * 32);
    }

    // ---- per-wave poll: wave w needs producers [16w, 16w+16), all 4 waves ----
    {
      const u32* fp = &flags[(bg * 64 + w * 16 + (lane & 15)) * 32];
      for (;;) {
        u32 f0 = __hip_atomic_load(fp + 0, __ATOMIC_RELAXED, __HIP_MEMORY_SCOPE_AGENT);
        u32 f1 = __hip_atomic_load(fp + 1, __ATOMIC_RELAXED, __HIP_MEMORY_SCOPE_AGENT);
        u32 f2 = __hip_atomic_load(fp + 2, __ATOMIC_RELAXED, __HIP_MEMORY_SCOPE_AGENT);
        u32 f3 = __hip_atomic_load(fp + 3, __ATOMIC_RELAXED, __HIP_MEMORY_SCOPE_AGENT);
        u32 mn = min(min(f0, f1), min(f2, f3));
        if (__ballot(mn < tag) == 0ull) break;
        __builtin_amdgcn_s_sleep(1);
      }
    }

    // ---- fetch own slice (guaranteed present), own 8 MFMAs + smH write ----
    u64 pay[16];
    PAYLOAD_LOAD;
    if      (w == 0) { OWN8(0)  }
    else if (w == 1) { OWN8(8)  }
    else if (w == 2) { OWN8(16) }
    else             { OWN8(24) }

    // ---- the ONE per-step barrier: smH[pb] ready (raw: x-loads stay in flight)
    asm volatile("s_waitcnt lgkmcnt(0)" ::: "memory");
    asm volatile("s_barrier" ::: "memory");
  }
}

extern "C" void kernel_launch(void* const* d_in, const int* in_sizes, int n_in,
                              void* d_out, int out_size, void* d_ws, size_t ws_size,
                              hipStream_t stream) {
  const float* x    = (const float*)d_in[0];
  const float* kern = (const float*)d_in[1];
  const float* rec  = (const float*)d_in[2];
  float* out = (float*)d_out;
  char* ws = (char*)d_ws;

  u16* xbp   = (u16*)(ws + WS_XB);
  u32* hbuf  = (u32*)(ws + WS_H);
  u32* flags = (u32*)(ws + WS_FLAG);

  // zero per-wave flags (ws is re-poisoned before every launch)
  hipMemsetAsync(ws + WS_FLAG, 0, 32768, stream);

  conv_x<<<8192, 256, 0, stream>>>(x, xbp);

  lstm_fused<<<256, 256, 0, stream>>>(kern, rec, xbp, hbuf, flags, out);
}

// Round 6
// 2939.898 us; speedup vs baseline: 1.1974x; 1.1974x over previous
//
#include <hip/hip_runtime.h>
#include <stdint.h>

// B=64, T=512, D=512, U=1024, 4U=4096
// Workspace (r0/r4 layout):
//   xb    : [T*64][512] bf16 = 33,554,432  (x as [t][b][d], bf16)
//   hbuf  : [2][64][512] u32 (packed bf16 pairs) = 262,144
//   flags : u32[256][32] = 32,768 (one 128-B line per WG flag, monotonic)
#define WS_XB   0LL
#define WS_H    33554432LL
#define WS_FLAG 33816576LL

typedef unsigned short u16;
typedef unsigned int   u32;
typedef unsigned long long u64;
typedef __attribute__((ext_vector_type(8))) short short8;
typedef __attribute__((ext_vector_type(4))) float f32x4;

__device__ __forceinline__ u16 f2bf(float f) {
  unsigned u = __float_as_uint(f);
  u += 0x7FFFu + ((u >> 16) & 1u);   // round-to-nearest-even
  return (u16)(u >> 16);
}
__device__ __forceinline__ float fast_tanh(float x) {
  float e = __expf(2.f * x);
  return 1.f - 2.f / (e + 1.f);
}

// ---------- conv: x [64][512][512] f32 -> xb [(t*64+b)][512] bf16 ----------
__global__ void conv_x(const float* __restrict__ x, u16* __restrict__ xb) {
  long gid = (long)blockIdx.x * blockDim.x + threadIdx.x;  // 2,097,152 threads
  long sr = gid >> 6;            // source row = b*512 + t
  int  d0 = (int)(gid & 63) * 8;
  int  b = (int)(sr >> 9), t = (int)(sr & 511);
  const float* src = x + sr * 512 + d0;
  float4 v0 = *(const float4*)(src);
  float4 v1 = *(const float4*)(src + 4);
  u16 tmp[8] = {f2bf(v0.x), f2bf(v0.y), f2bf(v0.z), f2bf(v0.w),
                f2bf(v1.x), f2bf(v1.y), f2bf(v1.z), f2bf(v1.w)};
  *(short8*)(xb + ((long)t * 64 + b) * 512 + d0) = *(short8*)tmp;
}

// ---------- fused LSTM: 256 WGs = 4 batch-groups x 64 u-tiles, persistent ----------
// r4 structure (best measured): packed hbuf, WG-granular flag after drain,
// wave0-only poll, single guaranteed fetch pass, gate-local columns, own-slice
// MFMAs from fetched regs, 3 raw s_barriers/step. Round-6 point fixes:
//   (a) split-drain: vmcnt(16) waits ONLY the publish store (vmcnt is ordered;
//       queue = [store, 16 x-loads]); x loads land under barrier+flag+poll.
//   (b) hard-spin poll (no s_sleep): finer detect granularity and avoids
//       SMU deep-idle downclock that inflates every RT's wall time.
__launch_bounds__(256, 1)
__global__ void lstm_fused(const float* __restrict__ kern, const float* __restrict__ rec,
                           const u16* __restrict__ xb, u32* __restrict__ hbuf,
                           u32* __restrict__ flags, float* __restrict__ out) {
  __shared__ u16   smH[2][32 * 64 * 8];   // 2 x 32,768 B, frag-ordered, dbuf
  __shared__ float zscr[4][16][20];       // per-wave z transpose scratch (pad 20)

  const int bid = blockIdx.x;
  const int bg = bid >> 6;   // 0..3 batch group (64 WGs each)
  const int ut = bid & 63;   // 0..63 u tile
  const int tid = threadIdx.x;
  const int w = tid >> 6, lane = tid & 63;
  const int quad = lane >> 4, n15 = lane & 15;
  const int gate = n15 >> 2, uu = n15 & 3;
  const int rowE = quad * 4 + gate;       // elementwise/publish row

  // ---- one-time: 48 register B-fragments, gate-local columns ----
  // wave w's col(n15) = gate*1024 + ut*16 + w*4 + uu
  short8 wf[48];
  const size_t gcol = (size_t)gate * 1024 + (size_t)ut * 16 + (size_t)(w * 4 + uu);
#pragma unroll
  for (int ks = 0; ks < 32; ++ks) {
    u16 tmp[8];
#pragma unroll
    for (int j = 0; j < 8; ++j)
      tmp[j] = f2bf(rec[(size_t)(ks * 32 + quad * 8 + j) * 4096 + gcol]);
    wf[ks] = *(short8*)tmp;
  }
#pragma unroll
  for (int ks = 0; ks < 16; ++ks) {
    u16 tmp[8];
#pragma unroll
    for (int j = 0; j < 8; ++j)
      tmp[j] = f2bf(kern[(size_t)(ks * 32 + quad * 8 + j) * 4096 + gcol]);
    wf[32 + ks] = *(short8*)tmp;
  }

  float c = 0.f;

  // ---- prologue: h0 = 0 in smH[0]; x0 A-frags -> regs; x-part MFMAs ----
#pragma unroll
  for (int j = 0; j < 8; ++j)
    *(uint4*)(&smH[0][(tid + j * 256) * 8]) = (uint4){0u, 0u, 0u, 0u};

  short8 xf[16];
  {
    const u16* xr = xb + (size_t)(bg * 16 + n15) * 512 + quad * 8;
#pragma unroll
    for (int ks = 0; ks < 16; ++ks) xf[ks] = *(const short8*)(xr + ks * 32);
  }
  f32x4 acc0 = {0.f, 0.f, 0.f, 0.f}, acc1 = {0.f, 0.f, 0.f, 0.f};
#pragma unroll
  for (int ks = 0; ks < 16; ks += 2) {
    acc0 = __builtin_amdgcn_mfma_f32_16x16x32_bf16(xf[ks], wf[32 + ks], acc0, 0, 0, 0);
    acc1 = __builtin_amdgcn_mfma_f32_16x16x32_bf16(xf[ks + 1], wf[33 + ks], acc1, 0, 0, 0);
  }
  __syncthreads();

#define X16_MFMA                                                                   \
  _Pragma("unroll")                                                                \
  for (int ks2 = 0; ks2 < 16; ks2 += 2) {                                          \
    acc0 = __builtin_amdgcn_mfma_f32_16x16x32_bf16(xf[ks2], wf[32 + ks2], acc0, 0, 0, 0);     \
    acc1 = __builtin_amdgcn_mfma_f32_16x16x32_bf16(xf[ks2 + 1], wf[33 + ks2], acc1, 0, 0, 0); \
  }

#define PAYLOAD_LOAD                                                               \
  {                                                                                \
    const u32* hs = hbuf + (size_t)pb * 32768 + (size_t)(bg * 16 + n15) * 512 + quad * 4; \
    _Pragma("unroll")                                                              \
    for (int kk = 0; kk < 8; ++kk) {                                               \
      const u64* src = (const u64*)(hs + (w * 8 + kk) * 16);                       \
      pay[2 * kk]     = __hip_atomic_load(src,     __ATOMIC_RELAXED, __HIP_MEMORY_SCOPE_AGENT); \
      pay[2 * kk + 1] = __hip_atomic_load(src + 1, __ATOMIC_RELAXED, __HIP_MEMORY_SCOPE_AGENT); \
    }                                                                              \
  }

#define OWN8(BASE)                                                                 \
  _Pragma("unroll")                                                                \
  for (int kk = 0; kk < 8; ++kk) {                                                 \
    union { u64 q[2]; short8 s; u32 d[4]; } uo;                                    \
    uo.q[0] = pay[2 * kk]; uo.q[1] = pay[2 * kk + 1];                              \
    if (kk & 1) acc1 = __builtin_amdgcn_mfma_f32_16x16x32_bf16(uo.s, wf[(BASE) + kk], acc1, 0, 0, 0); \
    else        acc0 = __builtin_amdgcn_mfma_f32_16x16x32_bf16(uo.s, wf[(BASE) + kk], acc0, 0, 0, 0); \
    *(uint4*)(smH[pb] + (((BASE) + kk) * 64 + lane) * 8) =                         \
        (uint4){uo.d[0], uo.d[1], uo.d[2], uo.d[3]};                               \
  }

  for (int t = 0; t < 512; ++t) {
    // ---- foreign 24 h-MFMAs from smH[t&1] (own 8 were done pre-barrier) ----
    const u16* sh = smH[t & 1];
#pragma unroll
    for (int g = 0; g < 4; ++g) {
      if (g == w) continue;                       // wave-uniform skip
#pragma unroll
      for (int kk = 0; kk < 8; kk += 2) {
        const int ks = g * 8 + kk;
        short8 a0 = *(const short8*)(sh + (ks * 64 + lane) * 8);
        acc0 = __builtin_amdgcn_mfma_f32_16x16x32_bf16(a0, wf[ks], acc0, 0, 0, 0);
        short8 a1 = *(const short8*)(sh + ((ks + 1) * 64 + lane) * 8);
        acc1 = __builtin_amdgcn_mfma_f32_16x16x32_bf16(a1, wf[ks + 1], acc1, 0, 0, 0);
      }
    }

    // ---- within-wave gate transpose via private LDS scratch (no barrier) ----
    const int cw = uu * 4 + gate;
    zscr[w][quad * 4 + 0][cw] = acc0[0] + acc1[0];
    zscr[w][quad * 4 + 1][cw] = acc0[1] + acc1[1];
    zscr[w][quad * 4 + 2][cw] = acc0[2] + acc1[2];
    zscr[w][quad * 4 + 3][cw] = acc0[3] + acc1[3];
    asm volatile("s_waitcnt lgkmcnt(0)" ::: "memory");
    __builtin_amdgcn_sched_barrier(0);
    float4 zv = *(const float4*)&zscr[w][rowE][uu * 4];   // (i,f,g,o)

    float ig = 1.f / (1.f + __expf(-zv.x));
    float fg = 1.f / (1.f + __expf(-zv.y));
    float gg = fast_tanh(zv.z);
    float og = 1.f / (1.f + __expf(-zv.w));
    c = fg * c + ig * gg;
    float h = og * fast_tanh(c);

    if (t == 511) {
      out[(size_t)(bg * 16 + rowE) * 1024 + (size_t)(ut * 16 + w * 4 + uu)] = h;
      break;
    }

    const int pb = (t + 1) & 1;

    // ---- publish packed: pair via shfl, even-uu lanes store one u32 ----
    {
      u16 hu = f2bf(h);
      int other = __shfl_xor((int)(unsigned)hu, 1);
      if ((uu & 1) == 0) {
        u32 pw = (u32)hu | ((u32)(unsigned)other << 16);
        __hip_atomic_store(&hbuf[(size_t)pb * 32768 + (size_t)(bg * 16 + rowE) * 512
                                 + ut * 8 + w * 2 + (uu >> 1)],
                           pw, __ATOMIC_RELAXED, __HIP_MEMORY_SCOPE_AGENT);
      }
    }
    __builtin_amdgcn_sched_barrier(0);   // pin: store issued before x loads

    // ---- x_{t+1} A-frag prefetch issue (NOT drained before the flag) ----
    {
      const u16* xr = xb + ((size_t)(t + 1) * 64 + bg * 16 + n15) * 512 + quad * 8;
#pragma unroll
      for (int ks2 = 0; ks2 < 16; ++ks2) xf[ks2] = *(const short8*)(xr + ks2 * 32);
    }
    __builtin_amdgcn_sched_barrier(0);   // pin: loads issued before the waitcnt

    // ---- split-drain: wait ONLY the publish store (16 loads still in flight)
    asm volatile("s_waitcnt vmcnt(16)" ::: "memory");
    asm volatile("s_barrier" ::: "memory");        // sync2: all waves' h acked
    if (tid == 0)
      __hip_atomic_store(&flags[(bg * 64 + ut) * 32], (u32)(t + 1),
                         __ATOMIC_RELAXED, __HIP_MEMORY_SCOPE_AGENT);

    acc0 = (f32x4){0.f, 0.f, 0.f, 0.f};
    acc1 = (f32x4){0.f, 0.f, 0.f, 0.f};

    u64 pay[16];
    if (w == 0) {
      // ---- wave0: hard-spin poll of 64 WG flags (1 line/lane, no s_sleep) ----
      const u32 tgt = (u32)(t + 1);
      const u32* fp = &flags[(bg * 64 + lane) * 32];
      u32 v = __hip_atomic_load(fp, __ATOMIC_RELAXED, __HIP_MEMORY_SCOPE_AGENT);
      while (__ballot(v < tgt) != 0ull) {
        v = __hip_atomic_load(fp, __ATOMIC_RELAXED, __HIP_MEMORY_SCOPE_AGENT);
      }
      PAYLOAD_LOAD;            // issued pre-barrier, stays in flight across it
    } else {
      X16_MFMA;                // waves 1-3: x-part under the poll window
    }
    asm volatile("s_barrier" ::: "memory");        // sync3: flags confirmed (raw, no drain)
    if (w == 0) {
      X16_MFMA;                // wave0: x-part while its payload is in flight
    } else {
      PAYLOAD_LOAD;
    }

    // ---- own 8 h-MFMAs straight from fetched regs + smH[pb] write ----
    if      (w == 0) { OWN8(0)  }
    else if (w == 1) { OWN8(8)  }
    else if (w == 2) { OWN8(16) }
    else             { OWN8(24) }

    asm volatile("s_waitcnt lgkmcnt(0)" ::: "memory");
    asm volatile("s_barrier" ::: "memory");        // sync4: smH[pb] ready
  }
}

extern "C" void kernel_launch(void* const* d_in, const int* in_sizes, int n_in,
                              void* d_out, int out_size, void* d_ws, size_t ws_size,
                              hipStream_t stream) {
  const float* x    = (const float*)d_in[0];
  const float* kern = (const float*)d_in[1];
  const float* rec  = (const float*)d_in[2];
  float* out = (float*)d_out;
  char* ws = (char*)d_ws;

  u16* xbp   = (u16*)(ws + WS_XB);
  u32* hbuf  = (u32*)(ws + WS_H);
  u32* flags = (u32*)(ws + WS_FLAG);

  // zero WG flags (ws is re-poisoned before every launch)
  hipMemsetAsync(ws + WS_FLAG, 0, 32768, stream);

  conv_x<<<8192, 256, 0, stream>>>(x, xbp);

  lstm_fused<<<256, 256, 0, stream>>>(kern, rec, xbp, hbuf, flags, out);
}